// Round 7
// baseline (1010.182 us; speedup 1.0000x reference)
//
#include <hip/hip_runtime.h>
#include <hip/hip_fp16.h>

#define DMODEL 192
#define DINNER 384
#define NPOS   4096   // B*H*W = 4*32*32
#define SEQL   1024   // H*W
#define DSTATE 16
#define DTRANK 12

__device__ __forceinline__ float silu_f(float v) { return v * (1.f / (1.f + __expf(-v))); }

// ---------------------------------------------------------------------------
// K1: x_val = (x @ W_in)[:, :384]  (fp32). 1024 blocks x 384 thr, 4 pos/block.
// ---------------------------------------------------------------------------
__global__ void k1_inproj(const float* __restrict__ x, const float* __restrict__ W_in,
                          float* __restrict__ x_val) {
    __shared__ float xs[4 * DMODEL];
    const int t = threadIdx.x;          // output col 0..383
    const int pos0 = blockIdx.x << 2;
    for (int i = t; i < 4 * DMODEL; i += 384) xs[i] = x[pos0 * DMODEL + i];
    __syncthreads();

    float acc[4] = {0.f, 0.f, 0.f, 0.f};
    for (int c = 0; c < DMODEL; ++c) {
        float w = W_in[c * 768 + t];
#pragma unroll
        for (int g = 0; g < 4; ++g) acc[g] += w * xs[g * DMODEL + c];
    }
#pragma unroll
    for (int g = 0; g < 4; ++g) x_val[(pos0 + g) * DINNER + t] = acc[g];
}

// ---------------------------------------------------------------------------
// K2: depthwise conv3x3 + bias + silu -> u (fp16) ; xd = u @ W_x (44 cols).
//     4096 blocks x 384 thr (one position per block).
// ---------------------------------------------------------------------------
__global__ void k2_conv(const float* __restrict__ x_val,
                        const float* __restrict__ conv_w, const float* __restrict__ conv_b,
                        const float* __restrict__ W_x,
                        __half* __restrict__ u_out, float* __restrict__ xd_out) {
    __shared__ float us[DINNER];
    __shared__ float part[8 * 44];
    const int t = threadIdx.x;               // channel d
    const int pos = blockIdx.x;
    const int b = pos >> 10, hw = pos & 1023, h = hw >> 5, w = hw & 31;

    float acc = conv_b[t];
#pragma unroll
    for (int i = 0; i < 3; ++i) {
        int hh = h + i - 1;
        if (hh < 0 || hh > 31) continue;
#pragma unroll
        for (int j = 0; j < 3; ++j) {
            int ww = w + j - 1;
            if (ww < 0 || ww > 31) continue;
            acc += x_val[((b * 32 + hh) * 32 + ww) * DINNER + t] * conv_w[t * 9 + i * 3 + j];
        }
    }
    float uv = silu_f(acc);
    us[t] = uv;
    u_out[pos * DINNER + t] = __float2half(uv);
    __syncthreads();

    // xd[o] = sum_j us[j]*W_x[j*44+o], o<44 ; 8 partials of 48 each
    if (t < 352) {
        int o = t % 44, p = t / 44;
        float s = 0.f;
        int j0 = p * 48;
        for (int j = j0; j < j0 + 48; ++j) s += us[j] * W_x[j * 44 + o];
        part[p * 44 + o] = s;
    }
    __syncthreads();
    if (t < 44) {
        float s = 0.f;
#pragma unroll
        for (int p = 0; p < 8; ++p) s += part[p * 44 + t];
        xd_out[pos * 48 + t] = s;
    }
}

// K2b: zero R1 (x_val dead after k2; becomes y_acc).
__global__ void k2b_zero(float* __restrict__ y_acc) {
    int i = blockIdx.x * 256 + threadIdx.x;
    if (i < NPOS * DINNER) y_acc[i] = 0.f;
}

// ---------------------------------------------------------------------------
// K3: four directional scans — fp32-exact emulation of the reference's
//     cumsum formulation (decay=exp(cumsum) underflow semantics preserved).
//     384 blocks x 256 thr ; thread=(d_local, n); 16-lane butterfly over n.
// ---------------------------------------------------------------------------
__global__ void k3_scan(const __half* __restrict__ u, const float* __restrict__ xd,
                        const float* __restrict__ W_dt, const float* __restrict__ b_dt,
                        const float* __restrict__ A_log, const float* __restrict__ Dp,
                        float* __restrict__ y_acc) {
    const int t = threadIdx.x;
    const int n = t & 15, dl = t >> 4;
    const int bi = blockIdx.x;
    const int chunk = bi % 24;
    const int b = (bi / 24) % 4;
    const int dir = bi / 96;
    const int d = chunk * 16 + dl;

    const float A   = -__expf(A_log[d * DSTATE + n]);
    const float Dd  = Dp[d];
    const float bdt = b_dt[d];
    float wdt[DTRANK];
#pragma unroll
    for (int r = 0; r < DTRANK; ++r) wdt[r] = W_dt[r * DINNER + d];

    const __half* ub = u  + b * SEQL * DINNER;
    const float* xb  = xd + b * SEQL * 48;
    float* yb = y_acc + b * SEQL * DINNER;

    float cum = 0.f, S = 0.f;
    for (int l = 0; l < SEQL; ++l) {
        int s   = (dir & 1) ? (SEQL - 1 - l) : l;
        int pos = (dir & 2) ? (((s & 31) << 5) | (s >> 5)) : s;   // transpose for dirs 2,3
        const float* xr = xb + pos * 48;

        float raw = bdt;
#pragma unroll
        for (int r = 0; r < DTRANK; ++r) raw += xr[r] * wdt[r];
        float dtv = fmaxf(raw, 0.f) + log1pf(__expf(-fabsf(raw)));  // softplus
        float Bv  = xr[DTRANK + n];
        float Cv  = xr[DTRANK + DSTATE + n];
        float uv  = __half2float(ub[pos * DINNER + d]);

        cum += dtv * A;                      // dtv>=0, A<0 -> monotone non-increasing
        float decay = __expf(cum);           // underflows to 0 like the fp32 reference
        S += (dtv * Bv * uv) / (decay + 1e-12f);
        float h = decay * S;
        float c = h * Cv;
        c += __shfl_xor(c, 1);
        c += __shfl_xor(c, 2);
        c += __shfl_xor(c, 4);
        c += __shfl_xor(c, 8);
        if (n == 0) atomicAdd(&yb[pos * DINNER + d], c + uv * Dd);
    }
}

// ---------------------------------------------------------------------------
// K4: LayerNorm over 384 + gate silu(z) (z recomputed from x@W_in[:,384:])
//     + out-proj (384->192). 4096 blocks x 192 thr.
// ---------------------------------------------------------------------------
__global__ void k4_out(const float* __restrict__ y_acc,
                       const float* __restrict__ x, const float* __restrict__ W_in,
                       const float* __restrict__ gamma, const float* __restrict__ beta,
                       const float* __restrict__ W_out, float* __restrict__ out) {
    __shared__ float g_s[DINNER];
    __shared__ float xs2[DMODEL];
    __shared__ float red[6];
    const int t = threadIdx.x;          // 0..191
    const int pos = blockIdx.x;
    const int lane = t & 63, wave = t >> 6;

    xs2[t] = x[pos * DMODEL + t];

    float y0 = y_acc[pos * DINNER + t];
    float y1 = y_acc[pos * DINNER + t + 192];

    float s = y0 + y1;
#pragma unroll
    for (int off = 32; off > 0; off >>= 1) s += __shfl_xor(s, off);
    if (lane == 0) red[wave] = s;
    __syncthreads();
    float mu = (red[0] + red[1] + red[2]) * (1.f / 384.f);

    float d0 = y0 - mu, d1 = y1 - mu;
    float sq = d0 * d0 + d1 * d1;
#pragma unroll
    for (int off = 32; off > 0; off >>= 1) sq += __shfl_xor(sq, off);
    if (lane == 0) red[3 + wave] = sq;
    __syncthreads();
    float var = (red[3] + red[4] + red[5]) * (1.f / 384.f);
    float inv = rsqrtf(var + 1e-5f);

    // z cols t and t+192:  z_j = sum_c x[c] * W_in[c*768 + 384 + j]
    float z0 = 0.f, z1 = 0.f;
    for (int c = 0; c < DMODEL; ++c) {
        float xv = xs2[c];
        z0 += xv * W_in[c * 768 + 384 + t];
        z1 += xv * W_in[c * 768 + 576 + t];
    }

    float v0 = d0 * inv * gamma[t]       + beta[t];
    float v1 = d1 * inv * gamma[t + 192] + beta[t + 192];
    g_s[t]       = v0 * silu_f(z0);
    g_s[t + 192] = v1 * silu_f(z1);
    __syncthreads();

    float acc = 0.f;
    for (int dd = 0; dd < DINNER; ++dd) acc += g_s[dd] * W_out[dd * DMODEL + t];
    out[pos * DMODEL + t] = acc;
}

// ---------------------------------------------------------------------------
extern "C" void kernel_launch(void* const* d_in, const int* in_sizes, int n_in,
                              void* d_out, int out_size, void* d_ws, size_t ws_size,
                              hipStream_t stream) {
    (void)in_sizes; (void)n_in; (void)out_size; (void)ws_size;
    const float* x      = (const float*)d_in[0];
    const float* W_in   = (const float*)d_in[1];
    const float* conv_w = (const float*)d_in[2];
    const float* conv_b = (const float*)d_in[3];
    const float* W_x    = (const float*)d_in[4];
    const float* W_dt   = (const float*)d_in[5];
    const float* b_dt   = (const float*)d_in[6];
    const float* A_log  = (const float*)d_in[7];
    const float* Dp     = (const float*)d_in[8];
    const float* W_out  = (const float*)d_in[9];
    const float* gamma  = (const float*)d_in[10];
    const float* beta   = (const float*)d_in[11];

    // ws layout (9.75 MB, fits verified ws_size):
    //   R1:  x_val fp32 (k1->k2), then y_acc fp32 (k2b->k4)   6 MB
    //   u:   fp16                                              3 MB
    //   xd:  fp32 4096 x 48 (44 used)                          0.75 MB
    char* base = (char*)d_ws;
    float*  R1 = (float*)base;
    __half* u  = (__half*)(base + (size_t)NPOS * DINNER * 4);
    float*  xd = (float*)(base + (size_t)NPOS * DINNER * 4 + (size_t)NPOS * DINNER * 2);

    hipLaunchKernelGGL(k1_inproj, dim3(NPOS / 4), dim3(384), 0, stream, x, W_in, R1);
    hipLaunchKernelGGL(k2_conv, dim3(NPOS), dim3(384), 0, stream,
                       R1, conv_w, conv_b, W_x, u, xd);
    hipLaunchKernelGGL(k2b_zero, dim3((NPOS * DINNER + 255) / 256), dim3(256), 0, stream, R1);
    hipLaunchKernelGGL(k3_scan, dim3(384), dim3(256), 0, stream,
                       u, xd, W_dt, b_dt, A_log, Dp, R1);
    hipLaunchKernelGGL(k4_out, dim3(NPOS), dim3(192), 0, stream,
                       R1, x, W_in, gamma, beta, W_out, (float*)d_out);
}

// Round 8
// 508.485 us; speedup vs baseline: 1.9866x; 1.9866x over previous
//
#include <hip/hip_runtime.h>
#include <hip/hip_fp16.h>

#define DMODEL 192
#define DINNER 384
#define NPOS   4096   // B*H*W = 4*32*32
#define SEQL   1024   // H*W
#define DSTATE 16
#define DTRANK 12

__device__ __forceinline__ float silu_f(float v) { return v * (1.f / (1.f + __expf(-v))); }

// ---------------------------------------------------------------------------
// K1: x_val = (x @ W_in)[:, :384]  (fp32). 1024 blocks x 384 thr, 4 pos/block.
// ---------------------------------------------------------------------------
__global__ void k1_inproj(const float* __restrict__ x, const float* __restrict__ W_in,
                          float* __restrict__ x_val) {
    __shared__ float xs[4 * DMODEL];
    const int t = threadIdx.x;
    const int pos0 = blockIdx.x << 2;
    for (int i = t; i < 4 * DMODEL; i += 384) xs[i] = x[pos0 * DMODEL + i];
    __syncthreads();

    float acc[4] = {0.f, 0.f, 0.f, 0.f};
    for (int c = 0; c < DMODEL; ++c) {
        float w = W_in[c * 768 + t];
#pragma unroll
        for (int g = 0; g < 4; ++g) acc[g] += w * xs[g * DMODEL + c];
    }
#pragma unroll
    for (int g = 0; g < 4; ++g) x_val[(pos0 + g) * DINNER + t] = acc[g];
}

// ---------------------------------------------------------------------------
// K2: depthwise conv3x3 + bias + silu -> u (fp16) ; xd = u @ W_x (44 cols).
// ---------------------------------------------------------------------------
__global__ void k2_conv(const float* __restrict__ x_val,
                        const float* __restrict__ conv_w, const float* __restrict__ conv_b,
                        const float* __restrict__ W_x,
                        __half* __restrict__ u_out, float* __restrict__ xd_out) {
    __shared__ float us[DINNER];
    __shared__ float part[8 * 44];
    const int t = threadIdx.x;
    const int pos = blockIdx.x;
    const int b = pos >> 10, hw = pos & 1023, h = hw >> 5, w = hw & 31;

    float acc = conv_b[t];
#pragma unroll
    for (int i = 0; i < 3; ++i) {
        int hh = h + i - 1;
        if (hh < 0 || hh > 31) continue;
#pragma unroll
        for (int j = 0; j < 3; ++j) {
            int ww = w + j - 1;
            if (ww < 0 || ww > 31) continue;
            acc += x_val[((b * 32 + hh) * 32 + ww) * DINNER + t] * conv_w[t * 9 + i * 3 + j];
        }
    }
    float uv = silu_f(acc);
    us[t] = uv;
    u_out[pos * DINNER + t] = __float2half(uv);
    __syncthreads();

    if (t < 352) {
        int o = t % 44, p = t / 44;
        float s = 0.f;
        int j0 = p * 48;
        for (int j = j0; j < j0 + 48; ++j) s += us[j] * W_x[j * 44 + o];
        part[p * 44 + o] = s;
    }
    __syncthreads();
    if (t < 44) {
        float s = 0.f;
#pragma unroll
        for (int p = 0; p < 8; ++p) s += part[p * 44 + t];
        xd_out[pos * 48 + t] = s;
    }
}

// ---------------------------------------------------------------------------
// K2c: dt32[pos][d] = softplus(b_dt[d] + xd[pos,:12] @ W_dt[:,d])
//      EXACT same arithmetic order as the in-loop version -> bitwise identical.
//      4096 blocks x 384 thr.
// ---------------------------------------------------------------------------
__global__ void k2c_dt(const float* __restrict__ xd, const float* __restrict__ W_dt,
                       const float* __restrict__ b_dt, float* __restrict__ dt32) {
    const int t = threadIdx.x;               // d
    const int pos = blockIdx.x;
    const float* xr = xd + pos * 48;
    float raw = b_dt[t];
#pragma unroll
    for (int r = 0; r < DTRANK; ++r) raw += xr[r] * W_dt[r * DINNER + t];
    dt32[pos * DINNER + t] = fmaxf(raw, 0.f) + log1pf(__expf(-fabsf(raw)));
}

// K2b: zero R1 (x_val dead after k2; becomes y_acc).
__global__ void k2b_zero(float* __restrict__ y_acc) {
    int i = blockIdx.x * 256 + threadIdx.x;
    if (i < NPOS * DINNER) y_acc[i] = 0.f;
}

// ---------------------------------------------------------------------------
// K3 fast: four directional scans with precomputed dt and 8-deep load batching
//          (load addresses are state-independent -> latency overlapped).
//          384 blocks x 256 thr ; thread=(d_local, n); butterfly over n.
// ---------------------------------------------------------------------------
__global__ void k3_fast(const __half* __restrict__ u, const float* __restrict__ xd,
                        const float* __restrict__ dt32,
                        const float* __restrict__ A_log, const float* __restrict__ Dp,
                        float* __restrict__ y_acc) {
    const int t = threadIdx.x;
    const int n = t & 15, dl = t >> 4;
    const int bi = blockIdx.x;
    const int chunk = bi % 24;
    const int b = (bi / 24) % 4;
    const int dir = bi / 96;
    const int d = chunk * 16 + dl;

    const float A  = -__expf(A_log[d * DSTATE + n]);
    const float Dd = Dp[d];

    const __half* ub  = u    + b * SEQL * DINNER;
    const float* xb   = xd   + b * SEQL * 48;
    const float* dtb  = dt32 + b * SEQL * DINNER;
    float* yb = y_acc + b * SEQL * DINNER;

    float cum = 0.f, S = 0.f;
    for (int l0 = 0; l0 < SEQL; l0 += 8) {
        float dtv[8], Bv[8], Cv[8], uv[8];
        int   pk[8];
#pragma unroll
        for (int k = 0; k < 8; ++k) {
            int l   = l0 + k;
            int s   = (dir & 1) ? (SEQL - 1 - l) : l;
            int pos = (dir & 2) ? (((s & 31) << 5) | (s >> 5)) : s;
            pk[k]  = pos;
            dtv[k] = dtb[pos * DINNER + d];
            Bv[k]  = xb[pos * 48 + DTRANK + n];
            Cv[k]  = xb[pos * 48 + DTRANK + DSTATE + n];
            uv[k]  = __half2float(ub[pos * DINNER + d]);
        }
#pragma unroll
        for (int k = 0; k < 8; ++k) {
            cum += dtv[k] * A;
            float decay = __expf(cum);                 // underflow semantics preserved
            S += (dtv[k] * Bv[k] * uv[k]) / (decay + 1e-12f);
            float c = decay * S * Cv[k];
            c += __shfl_xor(c, 1);
            c += __shfl_xor(c, 2);
            c += __shfl_xor(c, 4);
            c += __shfl_xor(c, 8);
            if (n == 0) atomicAdd(&yb[pk[k] * DINNER + d], c + uv[k] * Dd);
        }
    }
}

// ---------------------------------------------------------------------------
// K3 slow (round-7 fallback, used only if ws_size can't hold dt32)
// ---------------------------------------------------------------------------
__global__ void k3_slow(const __half* __restrict__ u, const float* __restrict__ xd,
                        const float* __restrict__ W_dt, const float* __restrict__ b_dt,
                        const float* __restrict__ A_log, const float* __restrict__ Dp,
                        float* __restrict__ y_acc) {
    const int t = threadIdx.x;
    const int n = t & 15, dl = t >> 4;
    const int bi = blockIdx.x;
    const int chunk = bi % 24;
    const int b = (bi / 24) % 4;
    const int dir = bi / 96;
    const int d = chunk * 16 + dl;

    const float A   = -__expf(A_log[d * DSTATE + n]);
    const float Dd  = Dp[d];
    const float bdt = b_dt[d];
    float wdt[DTRANK];
#pragma unroll
    for (int r = 0; r < DTRANK; ++r) wdt[r] = W_dt[r * DINNER + d];

    const __half* ub = u  + b * SEQL * DINNER;
    const float* xb  = xd + b * SEQL * 48;
    float* yb = y_acc + b * SEQL * DINNER;

    float cum = 0.f, S = 0.f;
    for (int l = 0; l < SEQL; ++l) {
        int s   = (dir & 1) ? (SEQL - 1 - l) : l;
        int pos = (dir & 2) ? (((s & 31) << 5) | (s >> 5)) : s;
        const float* xr = xb + pos * 48;

        float raw = bdt;
#pragma unroll
        for (int r = 0; r < DTRANK; ++r) raw += xr[r] * wdt[r];
        float dtv = fmaxf(raw, 0.f) + log1pf(__expf(-fabsf(raw)));
        float Bv  = xr[DTRANK + n];
        float Cv  = xr[DTRANK + DSTATE + n];
        float uv  = __half2float(ub[pos * DINNER + d]);

        cum += dtv * A;
        float decay = __expf(cum);
        S += (dtv * Bv * uv) / (decay + 1e-12f);
        float c = decay * S * Cv;
        c += __shfl_xor(c, 1);
        c += __shfl_xor(c, 2);
        c += __shfl_xor(c, 4);
        c += __shfl_xor(c, 8);
        if (n == 0) atomicAdd(&yb[pos * DINNER + d], c + uv * Dd);
    }
}

// ---------------------------------------------------------------------------
// K4: LayerNorm over 384 + gate silu(z) (z recomputed) + out-proj (384->192).
// ---------------------------------------------------------------------------
__global__ void k4_out(const float* __restrict__ y_acc,
                       const float* __restrict__ x, const float* __restrict__ W_in,
                       const float* __restrict__ gamma, const float* __restrict__ beta,
                       const float* __restrict__ W_out, float* __restrict__ out) {
    __shared__ float g_s[DINNER];
    __shared__ float xs2[DMODEL];
    __shared__ float red[6];
    const int t = threadIdx.x;          // 0..191
    const int pos = blockIdx.x;
    const int lane = t & 63, wave = t >> 6;

    xs2[t] = x[pos * DMODEL + t];

    float y0 = y_acc[pos * DINNER + t];
    float y1 = y_acc[pos * DINNER + t + 192];

    float s = y0 + y1;
#pragma unroll
    for (int off = 32; off > 0; off >>= 1) s += __shfl_xor(s, off);
    if (lane == 0) red[wave] = s;
    __syncthreads();
    float mu = (red[0] + red[1] + red[2]) * (1.f / 384.f);

    float d0 = y0 - mu, d1 = y1 - mu;
    float sq = d0 * d0 + d1 * d1;
#pragma unroll
    for (int off = 32; off > 0; off >>= 1) sq += __shfl_xor(sq, off);
    if (lane == 0) red[3 + wave] = sq;
    __syncthreads();
    float var = (red[3] + red[4] + red[5]) * (1.f / 384.f);
    float inv = rsqrtf(var + 1e-5f);

    float z0 = 0.f, z1 = 0.f;
    for (int c = 0; c < DMODEL; ++c) {
        float xv = xs2[c];
        z0 += xv * W_in[c * 768 + 384 + t];
        z1 += xv * W_in[c * 768 + 576 + t];
    }

    float v0 = d0 * inv * gamma[t]       + beta[t];
    float v1 = d1 * inv * gamma[t + 192] + beta[t + 192];
    g_s[t]       = v0 * silu_f(z0);
    g_s[t + 192] = v1 * silu_f(z1);
    __syncthreads();

    float acc = 0.f;
    for (int dd = 0; dd < DINNER; ++dd) acc += g_s[dd] * W_out[dd * DMODEL + t];
    out[pos * DMODEL + t] = acc;
}

// ---------------------------------------------------------------------------
extern "C" void kernel_launch(void* const* d_in, const int* in_sizes, int n_in,
                              void* d_out, int out_size, void* d_ws, size_t ws_size,
                              hipStream_t stream) {
    (void)in_sizes; (void)n_in; (void)out_size;
    const float* x      = (const float*)d_in[0];
    const float* W_in   = (const float*)d_in[1];
    const float* conv_w = (const float*)d_in[2];
    const float* conv_b = (const float*)d_in[3];
    const float* W_x    = (const float*)d_in[4];
    const float* W_dt   = (const float*)d_in[5];
    const float* b_dt   = (const float*)d_in[6];
    const float* A_log  = (const float*)d_in[7];
    const float* Dp     = (const float*)d_in[8];
    const float* W_out  = (const float*)d_in[9];
    const float* gamma  = (const float*)d_in[10];
    const float* beta   = (const float*)d_in[11];

    // ws layout:
    //   R1:  x_val fp32 (k1->k2) then y_acc (k2b->k4)   6 MB
    //   u:   fp16                                        3 MB
    //   xd:  fp32 4096 x 48                              0.75 MB
    //   dt32: fp32 4096 x 384 (fast path only)           6 MB    -> 15.75 MB
    char* base = (char*)d_ws;
    float*  R1   = (float*)base;
    __half* u    = (__half*)(base + (size_t)NPOS * DINNER * 4);
    float*  xd   = (float*)(base + (size_t)NPOS * DINNER * 4 + (size_t)NPOS * DINNER * 2);
    float*  dt32 = (float*)(base + (size_t)NPOS * DINNER * 4 + (size_t)NPOS * DINNER * 2
                                 + (size_t)NPOS * 48 * 4);
    const size_t NEEDED_FAST = (size_t)NPOS * DINNER * 4 + (size_t)NPOS * DINNER * 2
                             + (size_t)NPOS * 48 * 4 + (size_t)NPOS * DINNER * 4;
    const bool fast = (ws_size >= NEEDED_FAST);

    hipLaunchKernelGGL(k1_inproj, dim3(NPOS / 4), dim3(384), 0, stream, x, W_in, R1);
    hipLaunchKernelGGL(k2_conv, dim3(NPOS), dim3(384), 0, stream,
                       R1, conv_w, conv_b, W_x, u, xd);
    if (fast) {
        hipLaunchKernelGGL(k2c_dt, dim3(NPOS), dim3(384), 0, stream, xd, W_dt, b_dt, dt32);
    }
    hipLaunchKernelGGL(k2b_zero, dim3((NPOS * DINNER + 255) / 256), dim3(256), 0, stream, R1);
    if (fast) {
        hipLaunchKernelGGL(k3_fast, dim3(384), dim3(256), 0, stream,
                           u, xd, dt32, A_log, Dp, R1);
    } else {
        hipLaunchKernelGGL(k3_slow, dim3(384), dim3(256), 0, stream,
                           u, xd, W_dt, b_dt, A_log, Dp, R1);
    }
    hipLaunchKernelGGL(k4_out, dim3(NPOS), dim3(192), 0, stream,
                       R1, x, W_in, gamma, beta, W_out, (float*)d_out);
}

// Round 9
// 368.994 us; speedup vs baseline: 2.7377x; 1.3780x over previous
//
#include <hip/hip_runtime.h>
#include <hip/hip_fp16.h>

#define DMODEL 192
#define DINNER 384
#define NPOS   4096   // B*H*W = 4*32*32
#define SEQL   1024   // H*W
#define DSTATE 16
#define DTRANK 12
#define NCH    8      // time chunks
#define CHL    128    // steps per chunk

__device__ __forceinline__ float silu_f(float v) { return v * (1.f / (1.f + __expf(-v))); }

__device__ __forceinline__ int scan_pos(int dir, int l) {
    int s = (dir & 1) ? (SEQL - 1 - l) : l;
    return (dir & 2) ? (((s & 31) << 5) | (s >> 5)) : s;
}

// ---------------------------------------------------------------------------
// K1 (fast): xz = x @ W_in, both halves. x_val fp32 + gz = silu(z).
//            512 blocks x 384 thr, 8 positions/block.
// ---------------------------------------------------------------------------
__global__ void k1_inproj8(const float* __restrict__ x, const float* __restrict__ W_in,
                           float* __restrict__ x_val, float* __restrict__ gz) {
    __shared__ float xs[8 * DMODEL];
    const int t = threadIdx.x;
    const int pos0 = blockIdx.x << 3;
    for (int i = t; i < 8 * DMODEL; i += 384) xs[i] = x[pos0 * DMODEL + i];
    __syncthreads();

    float a0[8] = {0,0,0,0,0,0,0,0};
    float a1[8] = {0,0,0,0,0,0,0,0};
    for (int c = 0; c < DMODEL; ++c) {
        float w0 = W_in[c * 768 + t];
        float w1 = W_in[c * 768 + 384 + t];
#pragma unroll
        for (int g = 0; g < 8; ++g) {
            float xv = xs[g * DMODEL + c];
            a0[g] += w0 * xv;
            a1[g] += w1 * xv;
        }
    }
#pragma unroll
    for (int g = 0; g < 8; ++g) {
        x_val[(pos0 + g) * DINNER + t] = a0[g];
        gz[(pos0 + g) * DINNER + t]    = silu_f(a1[g]);
    }
}

// K1 (fallback): x_val only, 4 pos/block.
__global__ void k1_inproj(const float* __restrict__ x, const float* __restrict__ W_in,
                          float* __restrict__ x_val) {
    __shared__ float xs[4 * DMODEL];
    const int t = threadIdx.x;
    const int pos0 = blockIdx.x << 2;
    for (int i = t; i < 4 * DMODEL; i += 384) xs[i] = x[pos0 * DMODEL + i];
    __syncthreads();
    float acc[4] = {0.f, 0.f, 0.f, 0.f};
    for (int c = 0; c < DMODEL; ++c) {
        float w = W_in[c * 768 + t];
#pragma unroll
        for (int g = 0; g < 4; ++g) acc[g] += w * xs[g * DMODEL + c];
    }
#pragma unroll
    for (int g = 0; g < 4; ++g) x_val[(pos0 + g) * DINNER + t] = acc[g];
}

// ---------------------------------------------------------------------------
// K2: depthwise conv3x3 + bias + silu -> u (fp16) ; xd = u @ W_x (44 cols).
// ---------------------------------------------------------------------------
__global__ void k2_conv(const float* __restrict__ x_val,
                        const float* __restrict__ conv_w, const float* __restrict__ conv_b,
                        const float* __restrict__ W_x,
                        __half* __restrict__ u_out, float* __restrict__ xd_out) {
    __shared__ float us[DINNER];
    __shared__ float part[8 * 44];
    const int t = threadIdx.x;
    const int pos = blockIdx.x;
    const int b = pos >> 10, hw = pos & 1023, h = hw >> 5, w = hw & 31;

    float acc = conv_b[t];
#pragma unroll
    for (int i = 0; i < 3; ++i) {
        int hh = h + i - 1;
        if (hh < 0 || hh > 31) continue;
#pragma unroll
        for (int j = 0; j < 3; ++j) {
            int ww = w + j - 1;
            if (ww < 0 || ww > 31) continue;
            acc += x_val[((b * 32 + hh) * 32 + ww) * DINNER + t] * conv_w[t * 9 + i * 3 + j];
        }
    }
    float uv = silu_f(acc);
    us[t] = uv;
    u_out[pos * DINNER + t] = __float2half(uv);
    __syncthreads();

    if (t < 352) {
        int o = t % 44, p = t / 44;
        float s = 0.f;
        int j0 = p * 48;
        for (int j = j0; j < j0 + 48; ++j) s += us[j] * W_x[j * 44 + o];
        part[p * 44 + o] = s;
    }
    __syncthreads();
    if (t < 44) {
        float s = 0.f;
#pragma unroll
        for (int p = 0; p < 8; ++p) s += part[p * 44 + t];
        xd_out[pos * 48 + t] = s;
    }
}

// K2c: dt32 = softplus(b_dt + xd[:, :12] @ W_dt)
__global__ void k2c_dt(const float* __restrict__ xd, const float* __restrict__ W_dt,
                       const float* __restrict__ b_dt, float* __restrict__ dt32) {
    const int t = threadIdx.x;
    const int pos = blockIdx.x;
    const float* xr = xd + pos * 48;
    float raw = b_dt[t];
#pragma unroll
    for (int r = 0; r < DTRANK; ++r) raw += xr[r] * W_dt[r * DINNER + t];
    dt32[pos * DINNER + t] = fmaxf(raw, 0.f) + log1pf(__expf(-fabsf(raw)));
}

// K2b: zero y_acc (reuses x_val region).
__global__ void k2b_zero(float* __restrict__ y_acc) {
    int i = blockIdx.x * 256 + threadIdx.x;
    if (i < NPOS * DINNER) y_acc[i] = 0.f;
}

// ---------------------------------------------------------------------------
// K3a: per-(dir,b,tchunk,d,n) cum chunk total = A * sum(dt over chunk).
//      3072 blocks x 256 thr; n-lanes split the 128 steps (8 each) + butterfly.
// ---------------------------------------------------------------------------
__global__ void k3a_cumtot(const float* __restrict__ dt32, const float* __restrict__ A_log,
                           float* __restrict__ cumA) {
    const int t = threadIdx.x;
    const int n = t & 15, dl = t >> 4;
    const int bi = blockIdx.x;
    const int tch = bi & 7;
    const int rest = bi >> 3;            // (dir*4+b)*24 + dchunk
    const int dchunk = rest % 24;
    const int db = rest / 24;            // dir*4+b
    const int b = db & 3, dir = db >> 2;
    const int d = dchunk * 16 + dl;

    const float A = -__expf(A_log[d * DSTATE + n]);
    const float* dtb = dt32 + b * SEQL * DINNER;

    float s = 0.f;
#pragma unroll
    for (int k = 0; k < 8; ++k) {
        int l = tch * CHL + n * 8 + k;
        s += dtb[scan_pos(dir, l) * DINNER + d];
    }
    s += __shfl_xor(s, 1);
    s += __shfl_xor(s, 2);
    s += __shfl_xor(s, 4);
    s += __shfl_xor(s, 8);
    cumA[(size_t)(db * 8 + tch) * 6144 + d * 16 + n] = A * s;
}

// K3p: in-place exclusive prefix over the 8 chunks, per (dir,b,d,n).
//      384 blocks x 256 thr.
__global__ void k3_prefix(float* __restrict__ arr) {
    int gid = blockIdx.x * 256 + threadIdx.x;   // 0..98303
    int db  = gid / 6144;
    int idx = gid % 6144;
    float* p = arr + (size_t)db * 8 * 6144 + idx;
    float run = 0.f;
#pragma unroll
    for (int c = 0; c < NCH; ++c) {
        float v = p[(size_t)c * 6144];
        p[(size_t)c * 6144] = run;
        run += v;
    }
}

// ---------------------------------------------------------------------------
// K3c: per-chunk S total, given cumstart. Same serial order as reference.
// ---------------------------------------------------------------------------
__global__ void k3c_stot(const __half* __restrict__ u, const float* __restrict__ xd,
                         const float* __restrict__ dt32, const float* __restrict__ A_log,
                         const float* __restrict__ cumA, float* __restrict__ SA) {
    const int t = threadIdx.x;
    const int n = t & 15, dl = t >> 4;
    const int bi = blockIdx.x;
    const int tch = bi & 7;
    const int rest = bi >> 3;
    const int dchunk = rest % 24;
    const int db = rest / 24;
    const int b = db & 3, dir = db >> 2;
    const int d = dchunk * 16 + dl;

    const float A = -__expf(A_log[d * DSTATE + n]);
    const size_t sidx = (size_t)(db * 8 + tch) * 6144 + d * 16 + n;

    const __half* ub  = u    + b * SEQL * DINNER;
    const float*  xb  = xd   + b * SEQL * 48;
    const float*  dtb = dt32 + b * SEQL * DINNER;

    float cum = cumA[sidx];
    float S = 0.f;
    for (int l0 = 0; l0 < CHL; l0 += 8) {
        float dtv[8], Bv[8], uv[8];
#pragma unroll
        for (int k = 0; k < 8; ++k) {
            int pos = scan_pos(dir, tch * CHL + l0 + k);
            dtv[k] = dtb[pos * DINNER + d];
            Bv[k]  = xb[pos * 48 + DTRANK + n];
            uv[k]  = __half2float(ub[pos * DINNER + d]);
        }
#pragma unroll
        for (int k = 0; k < 8; ++k) {
            cum += dtv[k] * A;
            float decay = __expf(cum);
            S += (dtv[k] * Bv[k] * uv[k]) / (decay + 1e-12f);
        }
    }
    SA[sidx] = S;
}

// ---------------------------------------------------------------------------
// K3e: final per-chunk scan seeded with (cumstart, Sstart); y += C.h + u.D.
// ---------------------------------------------------------------------------
__global__ void k3e_scan(const __half* __restrict__ u, const float* __restrict__ xd,
                         const float* __restrict__ dt32, const float* __restrict__ A_log,
                         const float* __restrict__ Dp,
                         const float* __restrict__ cumA, const float* __restrict__ SA,
                         float* __restrict__ y_acc) {
    const int t = threadIdx.x;
    const int n = t & 15, dl = t >> 4;
    const int bi = blockIdx.x;
    const int tch = bi & 7;
    const int rest = bi >> 3;
    const int dchunk = rest % 24;
    const int db = rest / 24;
    const int b = db & 3, dir = db >> 2;
    const int d = dchunk * 16 + dl;

    const float A  = -__expf(A_log[d * DSTATE + n]);
    const float Dd = Dp[d];
    const size_t sidx = (size_t)(db * 8 + tch) * 6144 + d * 16 + n;

    const __half* ub  = u    + b * SEQL * DINNER;
    const float*  xb  = xd   + b * SEQL * 48;
    const float*  dtb = dt32 + b * SEQL * DINNER;
    float* yb = y_acc + b * SEQL * DINNER;

    float cum = cumA[sidx];
    float S   = SA[sidx];
    for (int l0 = 0; l0 < CHL; l0 += 8) {
        float dtv[8], Bv[8], Cv[8], uv[8];
        int   pk[8];
#pragma unroll
        for (int k = 0; k < 8; ++k) {
            int pos = scan_pos(dir, tch * CHL + l0 + k);
            pk[k]  = pos;
            dtv[k] = dtb[pos * DINNER + d];
            Bv[k]  = xb[pos * 48 + DTRANK + n];
            Cv[k]  = xb[pos * 48 + DTRANK + DSTATE + n];
            uv[k]  = __half2float(ub[pos * DINNER + d]);
        }
#pragma unroll
        for (int k = 0; k < 8; ++k) {
            cum += dtv[k] * A;
            float decay = __expf(cum);
            S += (dtv[k] * Bv[k] * uv[k]) / (decay + 1e-12f);
            float c = decay * S * Cv[k];
            c += __shfl_xor(c, 1);
            c += __shfl_xor(c, 2);
            c += __shfl_xor(c, 4);
            c += __shfl_xor(c, 8);
            if (n == 0) atomicAdd(&yb[pk[k] * DINNER + d], c + uv[k] * Dd);
        }
    }
}

// ---------------------------------------------------------------------------
// K3 (fallback, round-8): single-pass serial scan with precomputed dt.
// ---------------------------------------------------------------------------
__global__ void k3_fast(const __half* __restrict__ u, const float* __restrict__ xd,
                        const float* __restrict__ dt32,
                        const float* __restrict__ A_log, const float* __restrict__ Dp,
                        float* __restrict__ y_acc) {
    const int t = threadIdx.x;
    const int n = t & 15, dl = t >> 4;
    const int bi = blockIdx.x;
    const int chunk = bi % 24;
    const int b = (bi / 24) % 4;
    const int dir = bi / 96;
    const int d = chunk * 16 + dl;

    const float A  = -__expf(A_log[d * DSTATE + n]);
    const float Dd = Dp[d];

    const __half* ub  = u    + b * SEQL * DINNER;
    const float* xb   = xd   + b * SEQL * 48;
    const float* dtb  = dt32 + b * SEQL * DINNER;
    float* yb = y_acc + b * SEQL * DINNER;

    float cum = 0.f, S = 0.f;
    for (int l0 = 0; l0 < SEQL; l0 += 8) {
        float dtv[8], Bv[8], Cv[8], uv[8];
        int   pk[8];
#pragma unroll
        for (int k = 0; k < 8; ++k) {
            int pos = scan_pos(dir, l0 + k);
            pk[k]  = pos;
            dtv[k] = dtb[pos * DINNER + d];
            Bv[k]  = xb[pos * 48 + DTRANK + n];
            Cv[k]  = xb[pos * 48 + DTRANK + DSTATE + n];
            uv[k]  = __half2float(ub[pos * DINNER + d]);
        }
#pragma unroll
        for (int k = 0; k < 8; ++k) {
            cum += dtv[k] * A;
            float decay = __expf(cum);
            S += (dtv[k] * Bv[k] * uv[k]) / (decay + 1e-12f);
            float c = decay * S * Cv[k];
            c += __shfl_xor(c, 1);
            c += __shfl_xor(c, 2);
            c += __shfl_xor(c, 4);
            c += __shfl_xor(c, 8);
            if (n == 0) atomicAdd(&yb[pk[k] * DINNER + d], c + uv[k] * Dd);
        }
    }
}

// ---------------------------------------------------------------------------
// K4 (fast): LayerNorm + gate by stored gz + out-proj. 1024 blocks x 192 thr,
//            4 positions/block (amortizes W_out L2 reads).
// ---------------------------------------------------------------------------
__global__ void k4_out4(const float* __restrict__ y_acc, const float* __restrict__ gz,
                        const float* __restrict__ gamma, const float* __restrict__ beta,
                        const float* __restrict__ W_out, float* __restrict__ out) {
    __shared__ float g_s[4 * DINNER];
    __shared__ float red[6];
    const int t = threadIdx.x;          // 0..191
    const int lane = t & 63, wave = t >> 6;
    const int pos0 = blockIdx.x << 2;

    const float g0c = gamma[t], g1c = gamma[t + 192];
    const float b0c = beta[t],  b1c = beta[t + 192];

    for (int p = 0; p < 4; ++p) {
        int pos = pos0 + p;
        float y0 = y_acc[pos * DINNER + t];
        float y1 = y_acc[pos * DINNER + t + 192];

        float s = y0 + y1;
#pragma unroll
        for (int off = 32; off > 0; off >>= 1) s += __shfl_xor(s, off);
        if (lane == 0) red[wave] = s;
        __syncthreads();
        float mu = (red[0] + red[1] + red[2]) * (1.f / 384.f);

        float d0 = y0 - mu, d1 = y1 - mu;
        float sq = d0 * d0 + d1 * d1;
#pragma unroll
        for (int off = 32; off > 0; off >>= 1) sq += __shfl_xor(sq, off);
        if (lane == 0) red[3 + wave] = sq;
        __syncthreads();
        float var = (red[3] + red[4] + red[5]) * (1.f / 384.f);
        float inv = rsqrtf(var + 1e-5f);

        g_s[p * DINNER + t]       = (d0 * inv * g0c + b0c) * gz[pos * DINNER + t];
        g_s[p * DINNER + t + 192] = (d1 * inv * g1c + b1c) * gz[pos * DINNER + t + 192];
    }
    __syncthreads();

    float acc[4] = {0.f, 0.f, 0.f, 0.f};
    for (int dd = 0; dd < DINNER; ++dd) {
        float w = W_out[dd * DMODEL + t];
#pragma unroll
        for (int p = 0; p < 4; ++p) acc[p] += g_s[p * DINNER + dd] * w;
    }
#pragma unroll
    for (int p = 0; p < 4; ++p) out[(pos0 + p) * DMODEL + t] = acc[p];
}

// K4 (fallback): recompute z from x @ W_in[:,384:]. 4096 x 192.
__global__ void k4_out(const float* __restrict__ y_acc,
                       const float* __restrict__ x, const float* __restrict__ W_in,
                       const float* __restrict__ gamma, const float* __restrict__ beta,
                       const float* __restrict__ W_out, float* __restrict__ out) {
    __shared__ float g_s[DINNER];
    __shared__ float xs2[DMODEL];
    __shared__ float red[6];
    const int t = threadIdx.x;
    const int pos = blockIdx.x;
    const int lane = t & 63, wave = t >> 6;

    xs2[t] = x[pos * DMODEL + t];
    float y0 = y_acc[pos * DINNER + t];
    float y1 = y_acc[pos * DINNER + t + 192];

    float s = y0 + y1;
#pragma unroll
    for (int off = 32; off > 0; off >>= 1) s += __shfl_xor(s, off);
    if (lane == 0) red[wave] = s;
    __syncthreads();
    float mu = (red[0] + red[1] + red[2]) * (1.f / 384.f);

    float d0 = y0 - mu, d1 = y1 - mu;
    float sq = d0 * d0 + d1 * d1;
#pragma unroll
    for (int off = 32; off > 0; off >>= 1) sq += __shfl_xor(sq, off);
    if (lane == 0) red[3 + wave] = sq;
    __syncthreads();
    float var = (red[3] + red[4] + red[5]) * (1.f / 384.f);
    float inv = rsqrtf(var + 1e-5f);

    float z0 = 0.f, z1 = 0.f;
    for (int c = 0; c < DMODEL; ++c) {
        float xv = xs2[c];
        z0 += xv * W_in[c * 768 + 384 + t];
        z1 += xv * W_in[c * 768 + 576 + t];
    }
    g_s[t]       = (d0 * inv * gamma[t]       + beta[t])       * silu_f(z0);
    g_s[t + 192] = (d1 * inv * gamma[t + 192] + beta[t + 192]) * silu_f(z1);
    __syncthreads();

    float acc = 0.f;
    for (int dd = 0; dd < DINNER; ++dd) acc += g_s[dd] * W_out[dd * DMODEL + t];
    out[pos * DMODEL + t] = acc;
}

// ---------------------------------------------------------------------------
extern "C" void kernel_launch(void* const* d_in, const int* in_sizes, int n_in,
                              void* d_out, int out_size, void* d_ws, size_t ws_size,
                              hipStream_t stream) {
    (void)in_sizes; (void)n_in; (void)out_size;
    const float* x      = (const float*)d_in[0];
    const float* W_in   = (const float*)d_in[1];
    const float* conv_w = (const float*)d_in[2];
    const float* conv_b = (const float*)d_in[3];
    const float* W_x    = (const float*)d_in[4];
    const float* W_dt   = (const float*)d_in[5];
    const float* b_dt   = (const float*)d_in[6];
    const float* A_log  = (const float*)d_in[7];
    const float* Dp     = (const float*)d_in[8];
    const float* W_out  = (const float*)d_in[9];
    const float* gamma  = (const float*)d_in[10];
    const float* beta   = (const float*)d_in[11];

    // ws layout:
    //  R1   x_val->y_acc fp32 : 6 MB      @ 0
    //  u    fp16              : 3 MB      @ 6291456
    //  xd   fp32 4096x48      : 0.75 MB   @ 9437184
    //  dt32 fp32              : 6 MB      @ 10223616
    //  gz   fp32 (fast only)  : 6 MB      @ 16515072
    //  cumA fp32 16x8x6144    : 3 MB      @ 22806528
    //  SA   fp32 16x8x6144    : 3 MB      @ 25952256   -> total 27.75 MB
    char* base = (char*)d_ws;
    float*  R1   = (float*)base;
    __half* u    = (__half*)(base + 6291456);
    float*  xd   = (float*)(base + 9437184);
    float*  dt32 = (float*)(base + 10223616);
    float*  gz   = (float*)(base + 16515072);
    float*  cumA = (float*)(base + 22806528);
    float*  SA   = (float*)(base + 25952256);

    const size_t NEEDED_NEW  = 29097984;   // 27.75 MB
    const size_t NEEDED_FAST = 16515072;   // round-8 path
    const int mode = (ws_size >= NEEDED_NEW) ? 2 : (ws_size >= NEEDED_FAST ? 1 : 0);

    if (mode == 2) {
        hipLaunchKernelGGL(k1_inproj8, dim3(NPOS / 8), dim3(384), 0, stream, x, W_in, R1, gz);
        hipLaunchKernelGGL(k2_conv, dim3(NPOS), dim3(384), 0, stream,
                           R1, conv_w, conv_b, W_x, u, xd);
        hipLaunchKernelGGL(k2c_dt, dim3(NPOS), dim3(384), 0, stream, xd, W_dt, b_dt, dt32);
        hipLaunchKernelGGL(k2b_zero, dim3((NPOS * DINNER + 255) / 256), dim3(256), 0, stream, R1);
        hipLaunchKernelGGL(k3a_cumtot, dim3(3072), dim3(256), 0, stream, dt32, A_log, cumA);
        hipLaunchKernelGGL(k3_prefix, dim3(384), dim3(256), 0, stream, cumA);
        hipLaunchKernelGGL(k3c_stot, dim3(3072), dim3(256), 0, stream,
                           u, xd, dt32, A_log, cumA, SA);
        hipLaunchKernelGGL(k3_prefix, dim3(384), dim3(256), 0, stream, SA);
        hipLaunchKernelGGL(k3e_scan, dim3(3072), dim3(256), 0, stream,
                           u, xd, dt32, A_log, Dp, cumA, SA, R1);
        hipLaunchKernelGGL(k4_out4, dim3(NPOS / 4), dim3(192), 0, stream,
                           R1, gz, gamma, beta, W_out, (float*)d_out);
    } else if (mode == 1) {
        hipLaunchKernelGGL(k1_inproj, dim3(NPOS / 4), dim3(384), 0, stream, x, W_in, R1);
        hipLaunchKernelGGL(k2_conv, dim3(NPOS), dim3(384), 0, stream,
                           R1, conv_w, conv_b, W_x, u, xd);
        hipLaunchKernelGGL(k2c_dt, dim3(NPOS), dim3(384), 0, stream, xd, W_dt, b_dt, dt32);
        hipLaunchKernelGGL(k2b_zero, dim3((NPOS * DINNER + 255) / 256), dim3(256), 0, stream, R1);
        hipLaunchKernelGGL(k3_fast, dim3(384), dim3(256), 0, stream,
                           u, xd, dt32, A_log, Dp, R1);
        hipLaunchKernelGGL(k4_out, dim3(NPOS), dim3(192), 0, stream,
                           R1, x, W_in, gamma, beta, W_out, (float*)d_out);
    }
    // mode 0: ws too small for any path (never observed; ws >= 15.75 MB verified round 8)
}

// Round 10
// 233.067 us; speedup vs baseline: 4.3343x; 1.5832x over previous
//
#include <hip/hip_runtime.h>
#include <hip/hip_fp16.h>

#define DMODEL 192
#define DINNER 384
#define NPOS   4096   // B*H*W = 4*32*32
#define SEQL   1024   // H*W
#define DSTATE 16
#define DTRANK 12

__device__ __forceinline__ float silu_f(float v) { return v * (1.f / (1.f + __expf(-v))); }

__device__ __forceinline__ int scan_pos(int dir, int l) {
    int s = (dir & 1) ? (SEQL - 1 - l) : l;
    return (dir & 2) ? (((s & 31) << 5) | (s >> 5)) : s;
}

// ---------------------------------------------------------------------------
// K1: xz = x @ W_in, both halves. x_val fp32 + gz = silu(z).
//     512 blocks x 384 thr, 8 positions/block.
// ---------------------------------------------------------------------------
__global__ void k1_inproj8(const float* __restrict__ x, const float* __restrict__ W_in,
                           float* __restrict__ x_val, float* __restrict__ gz) {
    __shared__ float xs[8 * DMODEL];
    const int t = threadIdx.x;
    const int pos0 = blockIdx.x << 3;
    for (int i = t; i < 8 * DMODEL; i += 384) xs[i] = x[pos0 * DMODEL + i];
    __syncthreads();

    float a0[8] = {0,0,0,0,0,0,0,0};
    float a1[8] = {0,0,0,0,0,0,0,0};
    for (int c = 0; c < DMODEL; ++c) {
        float w0 = W_in[c * 768 + t];
        float w1 = W_in[c * 768 + 384 + t];
#pragma unroll
        for (int g = 0; g < 8; ++g) {
            float xv = xs[g * DMODEL + c];
            a0[g] += w0 * xv;
            a1[g] += w1 * xv;
        }
    }
#pragma unroll
    for (int g = 0; g < 8; ++g) {
        x_val[(pos0 + g) * DINNER + t] = a0[g];
        gz[(pos0 + g) * DINNER + t]    = silu_f(a1[g]);
    }
}

// ---------------------------------------------------------------------------
// K2: depthwise conv3x3 + bias + silu -> u (fp16) ; xd = u @ W_x (44 cols).
// ---------------------------------------------------------------------------
__global__ void k2_conv(const float* __restrict__ x_val,
                        const float* __restrict__ conv_w, const float* __restrict__ conv_b,
                        const float* __restrict__ W_x,
                        __half* __restrict__ u_out, float* __restrict__ xd_out) {
    __shared__ float us[DINNER];
    __shared__ float part[8 * 44];
    const int t = threadIdx.x;
    const int pos = blockIdx.x;
    const int b = pos >> 10, hw = pos & 1023, h = hw >> 5, w = hw & 31;

    float acc = conv_b[t];
#pragma unroll
    for (int i = 0; i < 3; ++i) {
        int hh = h + i - 1;
        if (hh < 0 || hh > 31) continue;
#pragma unroll
        for (int j = 0; j < 3; ++j) {
            int ww = w + j - 1;
            if (ww < 0 || ww > 31) continue;
            acc += x_val[((b * 32 + hh) * 32 + ww) * DINNER + t] * conv_w[t * 9 + i * 3 + j];
        }
    }
    float uv = silu_f(acc);
    us[t] = uv;
    u_out[pos * DINNER + t] = __float2half(uv);
    __syncthreads();

    if (t < 352) {
        int o = t % 44, p = t / 44;
        float s = 0.f;
        int j0 = p * 48;
        for (int j = j0; j < j0 + 48; ++j) s += us[j] * W_x[j * 44 + o];
        part[p * 44 + o] = s;
    }
    __syncthreads();
    if (t < 44) {
        float s = 0.f;
#pragma unroll
        for (int p = 0; p < 8; ++p) s += part[p * 44 + t];
        xd_out[pos * 48 + t] = s;
    }
}

// ---------------------------------------------------------------------------
// K2c: dt32 = softplus(b_dt + xd[:, :12] @ W_dt)  AND  y_acc init = 4*D*u
//      (u*D term of all four scans hoisted out of k3). 4096 blocks x 384 thr.
//      Runs after k2 (x_val region dead -> safe to overwrite as y_acc).
// ---------------------------------------------------------------------------
__global__ void k2c_dt_init(const float* __restrict__ xd, const float* __restrict__ W_dt,
                            const float* __restrict__ b_dt, const __half* __restrict__ u,
                            const float* __restrict__ Dp,
                            float* __restrict__ dt32, float* __restrict__ y_acc) {
    const int t = threadIdx.x;
    const int pos = blockIdx.x;
    const float* xr = xd + pos * 48;
    float raw = b_dt[t];
#pragma unroll
    for (int r = 0; r < DTRANK; ++r) raw += xr[r] * W_dt[r * DINNER + t];
    dt32[pos * DINNER + t] = fmaxf(raw, 0.f) + log1pf(__expf(-fabsf(raw)));

    y_acc[pos * DINNER + t] = 4.f * Dp[t] * __half2float(u[pos * DINNER + t]);
}

// ---------------------------------------------------------------------------
// K3: single-pass directional scan with wave-ballot early exit.
//     Once cum < -110 for a lane, exp(cum)==0 in fp32 (even denormal) forever
//     (cum monotone non-increasing), so every future c contribution is exactly
//     0*S*C = 0 -> skipping is bitwise-safe. Wave exits when all 64 lanes dead.
//     384 blocks x 256 thr ; thread=(d_local, n); butterfly over n.
// ---------------------------------------------------------------------------
__global__ void k3_early(const __half* __restrict__ u, const float* __restrict__ xd,
                         const float* __restrict__ dt32, const float* __restrict__ A_log,
                         float* __restrict__ y_acc) {
    const int t = threadIdx.x;
    const int n = t & 15, dl = t >> 4;
    const int bi = blockIdx.x;
    const int chunk = bi % 24;
    const int b = (bi / 24) % 4;
    const int dir = bi / 96;
    const int d = chunk * 16 + dl;

    const float A = -__expf(A_log[d * DSTATE + n]);

    const __half* ub  = u    + b * SEQL * DINNER;
    const float* xb   = xd   + b * SEQL * 48;
    const float* dtb  = dt32 + b * SEQL * DINNER;
    float* yb = y_acc + b * SEQL * DINNER;

    float cum = 0.f, S = 0.f;
    for (int l0 = 0; l0 < SEQL; l0 += 8) {
        float dtv[8], Bv[8], Cv[8], uv[8];
        int   pk[8];
#pragma unroll
        for (int k = 0; k < 8; ++k) {
            int pos = scan_pos(dir, l0 + k);
            pk[k]  = pos;
            dtv[k] = dtb[pos * DINNER + d];
            Bv[k]  = xb[pos * 48 + DTRANK + n];
            Cv[k]  = xb[pos * 48 + DTRANK + DSTATE + n];
            uv[k]  = __half2float(ub[pos * DINNER + d]);
        }
#pragma unroll
        for (int k = 0; k < 8; ++k) {
            cum += dtv[k] * A;
            float decay = __expf(cum);                 // underflow semantics preserved
            S += (dtv[k] * Bv[k] * uv[k]) * __builtin_amdgcn_rcpf(decay + 1e-12f);
            float c = decay * S * Cv[k];
            c += __shfl_xor(c, 1);
            c += __shfl_xor(c, 2);
            c += __shfl_xor(c, 4);
            c += __shfl_xor(c, 8);
            if (n == 0) atomicAdd(&yb[pk[k] * DINNER + d], c);
        }
        if (__ballot(cum > -110.f) == 0ull) break;     // all lanes dead -> rest is exact 0
    }
}

// ---------------------------------------------------------------------------
// K4: LayerNorm + gate by stored gz + out-proj. 1024 blocks x 192 thr,
//     4 positions/block (amortizes W_out L2 reads).
// ---------------------------------------------------------------------------
__global__ void k4_out4(const float* __restrict__ y_acc, const float* __restrict__ gz,
                        const float* __restrict__ gamma, const float* __restrict__ beta,
                        const float* __restrict__ W_out, float* __restrict__ out) {
    __shared__ float g_s[4 * DINNER];
    __shared__ float red[6];
    const int t = threadIdx.x;          // 0..191
    const int lane = t & 63, wave = t >> 6;
    const int pos0 = blockIdx.x << 2;

    const float g0c = gamma[t], g1c = gamma[t + 192];
    const float b0c = beta[t],  b1c = beta[t + 192];

    for (int p = 0; p < 4; ++p) {
        int pos = pos0 + p;
        float y0 = y_acc[pos * DINNER + t];
        float y1 = y_acc[pos * DINNER + t + 192];

        float s = y0 + y1;
#pragma unroll
        for (int off = 32; off > 0; off >>= 1) s += __shfl_xor(s, off);
        if (lane == 0) red[wave] = s;
        __syncthreads();
        float mu = (red[0] + red[1] + red[2]) * (1.f / 384.f);

        float d0 = y0 - mu, d1 = y1 - mu;
        float sq = d0 * d0 + d1 * d1;
#pragma unroll
        for (int off = 32; off > 0; off >>= 1) sq += __shfl_xor(sq, off);
        if (lane == 0) red[3 + wave] = sq;
        __syncthreads();
        float var = (red[3] + red[4] + red[5]) * (1.f / 384.f);
        float inv = rsqrtf(var + 1e-5f);

        g_s[p * DINNER + t]       = (d0 * inv * g0c + b0c) * gz[pos * DINNER + t];
        g_s[p * DINNER + t + 192] = (d1 * inv * g1c + b1c) * gz[pos * DINNER + t + 192];
        __syncthreads();
    }

    float acc[4] = {0.f, 0.f, 0.f, 0.f};
    for (int dd = 0; dd < DINNER; ++dd) {
        float w = W_out[dd * DMODEL + t];
#pragma unroll
        for (int p = 0; p < 4; ++p) acc[p] += g_s[p * DINNER + dd] * w;
    }
#pragma unroll
    for (int p = 0; p < 4; ++p) out[(pos0 + p) * DMODEL + t] = acc[p];
}

// ---------------------------------------------------------------------------
extern "C" void kernel_launch(void* const* d_in, const int* in_sizes, int n_in,
                              void* d_out, int out_size, void* d_ws, size_t ws_size,
                              hipStream_t stream) {
    (void)in_sizes; (void)n_in; (void)out_size; (void)ws_size;
    const float* x      = (const float*)d_in[0];
    const float* W_in   = (const float*)d_in[1];
    const float* conv_w = (const float*)d_in[2];
    const float* conv_b = (const float*)d_in[3];
    const float* W_x    = (const float*)d_in[4];
    const float* W_dt   = (const float*)d_in[5];
    const float* b_dt   = (const float*)d_in[6];
    const float* A_log  = (const float*)d_in[7];
    const float* Dp     = (const float*)d_in[8];
    const float* W_out  = (const float*)d_in[9];
    const float* gamma  = (const float*)d_in[10];
    const float* beta   = (const float*)d_in[11];

    // ws layout (22.75 MB; >=27.75 MB verified available in round 9):
    //  R1   x_val fp32 (k1->k2) -> y_acc (k2c->k4) : 6 MB    @ 0
    //  u    fp16                                   : 3 MB    @ 6291456
    //  xd   fp32 4096x48                           : 0.75 MB @ 9437184
    //  dt32 fp32                                   : 6 MB    @ 10223616
    //  gz   fp32                                   : 6 MB    @ 16515072
    char* base = (char*)d_ws;
    float*  R1   = (float*)base;
    __half* u    = (__half*)(base + 6291456);
    float*  xd   = (float*)(base + 9437184);
    float*  dt32 = (float*)(base + 10223616);
    float*  gz   = (float*)(base + 16515072);

    hipLaunchKernelGGL(k1_inproj8, dim3(NPOS / 8), dim3(384), 0, stream, x, W_in, R1, gz);
    hipLaunchKernelGGL(k2_conv, dim3(NPOS), dim3(384), 0, stream,
                       R1, conv_w, conv_b, W_x, u, xd);
    hipLaunchKernelGGL(k2c_dt_init, dim3(NPOS), dim3(384), 0, stream,
                       xd, W_dt, b_dt, u, Dp, dt32, R1);
    hipLaunchKernelGGL(k3_early, dim3(384), dim3(256), 0, stream,
                       u, xd, dt32, A_log, R1);
    hipLaunchKernelGGL(k4_out4, dim3(NPOS / 4), dim3(192), 0, stream,
                       R1, gz, gamma, beta, W_out, (float*)d_out);
}